// Round 4
// baseline (478.366 us; speedup 1.0000x reference)
//
#include <hip/hip_runtime.h>
#include <hip/hip_bf16.h>
#include <math.h>

#define BATCH  2
#define SEQ    2048
#define HID    1024
#define INNER  2048
#define NSTATE 64
#define NTOK   (BATCH * SEQ)
#define TCHUNK 64
#define NCHUNK (SEQ / TCHUNK)

typedef __bf16 bf16x8 __attribute__((ext_vector_type(8)));
typedef float  f32x4  __attribute__((ext_vector_type(4)));

typedef const __attribute__((address_space(1))) char* gas_ptr;
typedef __attribute__((address_space(3))) char*       las_ptr;

__device__ __forceinline__ void gload16(const void* g, void* l) {
  __builtin_amdgcn_global_load_lds((gas_ptr)g, (las_ptr)l, 16, 0, 0);
}

__device__ __forceinline__ unsigned short f2bf(float f) {
  __hip_bfloat16 h = __float2bfloat16(f);
  return __builtin_bit_cast(unsigned short, h);
}
__device__ __forceinline__ float bf2f(unsigned short u) {
  unsigned int x = ((unsigned int)u) << 16;
  return __builtin_bit_cast(float, x);
}

// ---------------------------------------------------------------- cvt fp32->bf16
__global__ __launch_bounds__(256) void cvt_f32_bf16_kernel(
    const float* __restrict__ in, __hip_bfloat16* __restrict__ out, int n4) {
  int i = blockIdx.x * 256 + threadIdx.x;
  if (i >= n4) return;
  float4 v = ((const float4*)in)[i];
  ushort4 u;
  u.x = f2bf(v.x); u.y = f2bf(v.y); u.z = f2bf(v.z); u.w = f2bf(v.w);
  ((ushort4*)out)[i] = u;
}

// ------------------------------------------------- transpose fp32 [R][C] -> bf16 [C][ostride]
__global__ __launch_bounds__(256) void transpose_cvt_kernel(
    const float* __restrict__ in, __hip_bfloat16* __restrict__ out,
    int R, int C, int ostride) {
  __shared__ float tile[32][33];
  int tx = threadIdx.x & 31, ty = threadIdx.x >> 5;
  int c0 = blockIdx.x * 32, r0 = blockIdx.y * 32;
#pragma unroll
  for (int i = 0; i < 4; ++i)
    tile[ty + 8 * i][tx] = in[(size_t)(r0 + ty + 8 * i) * C + c0 + tx];
  __syncthreads();
#pragma unroll
  for (int i = 0; i < 4; ++i)
    out[(size_t)(c0 + ty + 8 * i) * ostride + r0 + tx] =
        __float2bfloat16(tile[tx][ty + 8 * i]);
}

// ---------------------------------------------------------------- GEMM: A[M,K] x Bt[N,K] -> C[M,N]
// m97 structure: BK=32, linear LDS [128][32], global_load_lds width-16 staging.
// EPI 0: fp32 store to Cout (ldc).
// EPI 1: split bf16 store: col<INNER -> o0 (xin), else -> o1 (z).
// EPI 2: mamba mid: col<INNER -> dt=softplus(v+bdt) to f0; next 64 -> f1 (Bm); next 64 -> f2 (Cm).
template <int EPI>
__global__ __launch_bounds__(256) void gemm_bt_kernel(
    const __hip_bfloat16* __restrict__ A, const __hip_bfloat16* __restrict__ Bt,
    int M, int N, int K,
    float* __restrict__ Cout, int ldc,
    const float* __restrict__ bdt,
    __hip_bfloat16* __restrict__ o0, __hip_bfloat16* __restrict__ o1,
    float* __restrict__ f0, float* __restrict__ f1, float* __restrict__ f2) {
  __shared__ __align__(16) __hip_bfloat16 As[128 * 32];
  __shared__ __align__(16) __hip_bfloat16 Bs[128 * 32];
  const int tid = threadIdx.x;
  const int lane = tid & 63;
  const int wave = tid >> 6;
  const int wr = wave >> 1, wc = wave & 1;
  const int m0 = blockIdx.y * 128, n0 = blockIdx.x * 128;
  const int lrow = lane & 15, lk = lane >> 4;

  f32x4 acc[4][4];
#pragma unroll
  for (int i = 0; i < 4; ++i)
#pragma unroll
    for (int j = 0; j < 4; ++j)
#pragma unroll
      for (int r = 0; r < 4; ++r) acc[i][j][r] = 0.f;

  // staging: wave w stages rows [w*32, w*32+32) of both A and B tiles.
  // Each global_load_lds covers 16 rows (64 lanes x 16B = 16 rows x 64B).
  const int srow = wave * 32;
  const int lr = lane >> 2;          // row within 16-row group
  const int lc = (lane & 3) * 8;     // col element (8 bf16 = 16B)
  const __hip_bfloat16* Ag0 = A  + (size_t)(m0 + srow + lr) * K + lc;
  const __hip_bfloat16* Ag1 = A  + (size_t)(m0 + srow + 16 + lr) * K + lc;
  const __hip_bfloat16* Bg0 = Bt + (size_t)(n0 + srow + lr) * K + lc;
  const __hip_bfloat16* Bg1 = Bt + (size_t)(n0 + srow + 16 + lr) * K + lc;
  __hip_bfloat16* lA0 = &As[(size_t)srow * 32];
  __hip_bfloat16* lA1 = &As[(size_t)(srow + 16) * 32];
  __hip_bfloat16* lB0 = &Bs[(size_t)srow * 32];
  __hip_bfloat16* lB1 = &Bs[(size_t)(srow + 16) * 32];

  for (int k0 = 0; k0 < K; k0 += 32) {
    __syncthreads();
    gload16(Ag0 + k0, lA0);
    gload16(Ag1 + k0, lA1);
    gload16(Bg0 + k0, lB0);
    gload16(Bg1 + k0, lB1);
    __syncthreads();  // drains vmcnt(0): staged tile visible to all waves
    bf16x8 af[4], bv[4];
#pragma unroll
    for (int i = 0; i < 4; ++i) {
      af[i] = *reinterpret_cast<const bf16x8*>(&As[(size_t)(wr * 64 + i * 16 + lrow) * 32 + lk * 8]);
      bv[i] = *reinterpret_cast<const bf16x8*>(&Bs[(size_t)(wc * 64 + i * 16 + lrow) * 32 + lk * 8]);
    }
#pragma unroll
    for (int i = 0; i < 4; ++i)
#pragma unroll
      for (int j = 0; j < 4; ++j)
        acc[i][j] = __builtin_amdgcn_mfma_f32_16x16x32_bf16(af[i], bv[j], acc[i][j], 0, 0, 0);
  }

#pragma unroll
  for (int i = 0; i < 4; ++i) {
#pragma unroll
    for (int j = 0; j < 4; ++j) {
#pragma unroll
      for (int r = 0; r < 4; ++r) {
        const int row = m0 + wr * 64 + i * 16 + lk * 4 + r;
        const int col = n0 + wc * 64 + j * 16 + lrow;
        const float v = acc[i][j][r];
        if constexpr (EPI == 0) {
          Cout[(size_t)row * ldc + col] = v;
        } else if constexpr (EPI == 1) {
          if (col < INNER) o0[(size_t)row * INNER + col] = __float2bfloat16(v);
          else             o1[(size_t)row * INNER + (col - INNER)] = __float2bfloat16(v);
        } else {
          if (col < INNER) {
            const float vv = v + bdt[col];
            const float dt = (vv > 15.f) ? vv : log1pf(expf(vv));
            f0[(size_t)row * INNER + col] = dt;
          } else {
            const int jn = col - INNER;
            if (jn < NSTATE) f1[(size_t)row * NSTATE + jn] = v;
            else             f2[(size_t)row * NSTATE + (jn - NSTATE)] = v;
          }
        }
      }
    }
  }
}

// ---------------------------------------------------------------- causal depthwise conv + silu (bf16 in, bf16 out)
__global__ __launch_bounds__(256) void conv_silu_kernel(
    const __hip_bfloat16* __restrict__ xin, const float* __restrict__ cw,
    const float* __restrict__ cb, __hip_bfloat16* __restrict__ xch) {
  int idx = blockIdx.x * 256 + threadIdx.x;  // NTOK * (INNER/4)
  int cg = idx & 511;
  int tok = idx >> 9;
  int c = cg * 4;
  int l = tok & (SEQ - 1);
  float wv[4][4];
#pragma unroll
  for (int i = 0; i < 4; ++i) {
    float4 w = *(const float4*)&cw[(c + i) * 4];
    wv[i][0] = w.x; wv[i][1] = w.y; wv[i][2] = w.z; wv[i][3] = w.w;
  }
  float4 bias = *(const float4*)&cb[c];
  float r0 = bias.x, r1 = bias.y, r2 = bias.z, r3 = bias.w;
#pragma unroll
  for (int k = 0; k < 4; ++k) {
    const int d = 3 - k;
    if (l >= d) {
      ushort4 xv = *(const ushort4*)&xin[(size_t)(tok - d) * INNER + c];
      r0 = fmaf(bf2f(xv.x), wv[0][k], r0);
      r1 = fmaf(bf2f(xv.y), wv[1][k], r1);
      r2 = fmaf(bf2f(xv.z), wv[2][k], r2);
      r3 = fmaf(bf2f(xv.w), wv[3][k], r3);
    }
  }
  r0 = r0 / (1.f + __expf(-r0));
  r1 = r1 / (1.f + __expf(-r1));
  r2 = r2 / (1.f + __expf(-r2));
  r3 = r3 / (1.f + __expf(-r3));
  ushort4 u;
  u.x = f2bf(r0); u.y = f2bf(r1); u.z = f2bf(r2); u.w = f2bf(r3);
  *(ushort4*)&xch[(size_t)tok * INNER + c] = u;
}

// ---------------------------------------------------------------- scan phase 1 (within-chunk states only)
__global__ __launch_bounds__(256) void scan_state_kernel(
    const float* __restrict__ dtb, const __hip_bfloat16* __restrict__ xch,
    const float* __restrict__ Bm,
    float* __restrict__ S, float* __restrict__ A_chunk) {
  __shared__ float Bsh[TCHUNK][64];
  const int b = blockIdx.z, chunk = blockIdx.y;
  const int c = blockIdx.x * 256 + threadIdx.x;
  const int t0 = chunk * TCHUNK;
  for (int i = threadIdx.x; i < TCHUNK * 16; i += 256) {
    const int row = i >> 4, q = i & 15;
    *(float4*)&Bsh[row][q * 4] =
        *(const float4*)&Bm[((size_t)(b * SEQ + t0 + row)) * NSTATE + q * 4];
  }
  __syncthreads();
  float s[64];
#pragma unroll
  for (int n = 0; n < 64; ++n) s[n] = 0.f;
  float p = 1.f;
  const size_t base = (size_t)(b * SEQ + t0) * INNER + c;
  for (int t = 0; t < TCHUNK; ++t) {
    const float dtv = dtb[base + (size_t)t * INNER];
    const float at = __expf(-dtv);
    const float xc = __bfloat162float(xch[base + (size_t)t * INNER]);
    const float ut = dtv * xc;
    p *= at;
#pragma unroll
    for (int q = 0; q < 16; ++q) {
      const float4 bv = *(const float4*)&Bsh[t][q * 4];
      s[4 * q + 0] = fmaf(at, s[4 * q + 0], ut * bv.x);
      s[4 * q + 1] = fmaf(at, s[4 * q + 1], ut * bv.y);
      s[4 * q + 2] = fmaf(at, s[4 * q + 2], ut * bv.z);
      s[4 * q + 3] = fmaf(at, s[4 * q + 3], ut * bv.w);
    }
  }
  const size_t sbase = ((size_t)(b * NCHUNK + chunk) * INNER + c) * NSTATE;
#pragma unroll
  for (int q = 0; q < 16; ++q)
    *(float4*)&S[sbase + 4 * q] =
        make_float4(s[4 * q], s[4 * q + 1], s[4 * q + 2], s[4 * q + 3]);
  A_chunk[(size_t)(b * NCHUNK + chunk) * INNER + c] = p;
}

// ---------------------------------------------------------------- scan phase 2 (cross-chunk combine, in place)
__global__ __launch_bounds__(256) void scan_combine_kernel(
    float* __restrict__ S, const float* __restrict__ A_chunk) {
  const int idx = blockIdx.x * 256 + threadIdx.x;  // BATCH*INNER*NSTATE
  const int n = idx & 63;
  const int c = (idx >> 6) & (INNER - 1);
  const int b = idx >> 17;
  float s = 0.f;
  for (int k = 0; k < NCHUNK; ++k) {
    const size_t cs = (size_t)(b * NCHUNK + k) * INNER + c;
    const size_t off = cs * NSTATE + n;
    const float loc = S[off];
    S[off] = s;
    s = fmaf(A_chunk[cs], s, loc);
  }
}

// ---------------------------------------------------------------- scan phase 3 (full scan from prefix + skip + gate)
__global__ __launch_bounds__(256) void scan_out_kernel(
    const float* __restrict__ dtb, const __hip_bfloat16* __restrict__ xch,
    const float* __restrict__ Bm, const float* __restrict__ Cm,
    const float* __restrict__ S_in, const __hip_bfloat16* __restrict__ zbf,
    const float* __restrict__ Dv, __hip_bfloat16* __restrict__ ygated) {
  __shared__ float Bsh[TCHUNK][64];
  __shared__ float Csh[TCHUNK][64];
  const int b = blockIdx.z, chunk = blockIdx.y;
  const int c = blockIdx.x * 256 + threadIdx.x;
  const int t0 = chunk * TCHUNK;
  for (int i = threadIdx.x; i < TCHUNK * 16; i += 256) {
    const int row = i >> 4, q = i & 15;
    const size_t src = ((size_t)(b * SEQ + t0 + row)) * NSTATE + q * 4;
    *(float4*)&Bsh[row][q * 4] = *(const float4*)&Bm[src];
    *(float4*)&Csh[row][q * 4] = *(const float4*)&Cm[src];
  }
  __syncthreads();
  float s[64];
  const size_t sbase = ((size_t)(b * NCHUNK + chunk) * INNER + c) * NSTATE;
#pragma unroll
  for (int q = 0; q < 16; ++q) {
    const float4 v = *(const float4*)&S_in[sbase + 4 * q];
    s[4 * q] = v.x; s[4 * q + 1] = v.y; s[4 * q + 2] = v.z; s[4 * q + 3] = v.w;
  }
  const float Dc = Dv[c];
  const size_t base = (size_t)(b * SEQ + t0) * INNER + c;
  for (int t = 0; t < TCHUNK; ++t) {
    const float dtv = dtb[base + (size_t)t * INNER];
    const float at = __expf(-dtv);
    const float xc = __bfloat162float(xch[base + (size_t)t * INNER]);
    const float ut = dtv * xc;
    float y0 = 0.f, y1 = 0.f, y2 = 0.f, y3 = 0.f;
#pragma unroll
    for (int q = 0; q < 16; ++q) {
      const float4 bv = *(const float4*)&Bsh[t][q * 4];
      const float4 cv = *(const float4*)&Csh[t][q * 4];
      s[4 * q + 0] = fmaf(at, s[4 * q + 0], ut * bv.x);
      s[4 * q + 1] = fmaf(at, s[4 * q + 1], ut * bv.y);
      s[4 * q + 2] = fmaf(at, s[4 * q + 2], ut * bv.z);
      s[4 * q + 3] = fmaf(at, s[4 * q + 3], ut * bv.w);
      y0 = fmaf(s[4 * q + 0], cv.x, y0);
      y1 = fmaf(s[4 * q + 1], cv.y, y1);
      y2 = fmaf(s[4 * q + 2], cv.z, y2);
      y3 = fmaf(s[4 * q + 3], cv.w, y3);
    }
    const float yt = fmaf(Dc, xc, (y0 + y1) + (y2 + y3));
    const float z = __bfloat162float(zbf[base + (size_t)t * INNER]);
    const float g = z / (1.f + __expf(-z));
    ygated[base + (size_t)t * INNER] = __float2bfloat16(yt * g);
  }
}

// ---------------------------------------------------------------- launch
extern "C" void kernel_launch(void* const* d_in, const int* in_sizes, int n_in,
                              void* d_out, int out_size, void* d_ws, size_t ws_size,
                              hipStream_t stream) {
  const float* x      = (const float*)d_in[0];
  const float* W_in   = (const float*)d_in[1];
  const float* conv_w = (const float*)d_in[2];
  const float* conv_b = (const float*)d_in[3];
  const float* W_dt   = (const float*)d_in[4];
  const float* b_dt   = (const float*)d_in[5];
  const float* W_B    = (const float*)d_in[6];
  const float* W_C    = (const float*)d_in[7];
  const float* Dvec   = (const float*)d_in[8];
  const float* W_out  = (const float*)d_in[9];
  float* out = (float*)d_out;

  // ---- workspace layout (~127 MiB total) with lifetime-based aliasing ----
  char* p = (char*)d_ws;
  auto alloc = [&](size_t bytes) {
    char* r = p;
    p += (bytes + 255) & ~(size_t)255;
    return r;
  };
  __hip_bfloat16* xin   = (__hip_bfloat16*)alloc((size_t)NTOK * INNER * 2);  // GEMM1 out; later ygated
  __hip_bfloat16* zbf   = (__hip_bfloat16*)alloc((size_t)NTOK * INNER * 2);
  char*           scr   = alloc((size_t)NTOK * INNER * 2);                   // x_bf+WinT; later xch
  __hip_bfloat16* WmidT = (__hip_bfloat16*)alloc((size_t)(INNER + 2 * NSTATE) * INNER * 2);
  __hip_bfloat16* WoutT = (__hip_bfloat16*)alloc((size_t)HID * INNER * 2);
  float*          dtb   = (float*)alloc((size_t)NTOK * INNER * 4);
  float*          Bm    = (float*)alloc((size_t)NTOK * NSTATE * 4);
  float*          Cm    = (float*)alloc((size_t)NTOK * NSTATE * 4);
  float*          S     = (float*)alloc((size_t)BATCH * NCHUNK * INNER * NSTATE * 4);
  float*          A_chk = (float*)alloc((size_t)BATCH * NCHUNK * INNER * 4);

  __hip_bfloat16* x_bf   = (__hip_bfloat16*)scr;                              // 8 MB
  __hip_bfloat16* WinT   = (__hip_bfloat16*)(scr + (size_t)NTOK * HID * 2);   // 8 MB
  __hip_bfloat16* xch    = (__hip_bfloat16*)scr;                              // 16 MB (after GEMM1)
  __hip_bfloat16* ygated = xin;                                               // 16 MB (after conv)

  // 1. conversions / transposes
  cvt_f32_bf16_kernel<<<(NTOK * HID / 4 + 255) / 256, 256, 0, stream>>>(x, x_bf, NTOK * HID / 4);
  transpose_cvt_kernel<<<dim3((2 * INNER) / 32, HID / 32), 256, 0, stream>>>(W_in, WinT, HID, 2 * INNER, HID);
  transpose_cvt_kernel<<<dim3(INNER / 32, INNER / 32), 256, 0, stream>>>(W_dt, WmidT, INNER, INNER, INNER);
  transpose_cvt_kernel<<<dim3(NSTATE / 32, INNER / 32), 256, 0, stream>>>(
      W_B, WmidT + (size_t)INNER * INNER, INNER, NSTATE, INNER);
  transpose_cvt_kernel<<<dim3(NSTATE / 32, INNER / 32), 256, 0, stream>>>(
      W_C, WmidT + (size_t)(INNER + NSTATE) * INNER, INNER, NSTATE, INNER);
  transpose_cvt_kernel<<<dim3(HID / 32, INNER / 32), 256, 0, stream>>>(W_out, WoutT, INNER, HID, INNER);

  // 2. xz = x @ W_in  -> split bf16 (xin | z)
  gemm_bt_kernel<1><<<dim3((2 * INNER) / 128, NTOK / 128), 256, 0, stream>>>(
      x_bf, WinT, NTOK, 2 * INNER, HID, nullptr, 0,
      nullptr, xin, zbf, nullptr, nullptr, nullptr);

  // 3. conv + silu  (xin -> xch; overwrites x_bf/WinT region)
  conv_silu_kernel<<<(NTOK * (INNER / 4)) / 256, 256, 0, stream>>>(xin, conv_w, conv_b, xch);

  // 4. mid GEMM (dt|B|C) with fused softplus epilogue
  gemm_bt_kernel<2><<<dim3((INNER + 2 * NSTATE) / 128, NTOK / 128), 256, 0, stream>>>(
      xch, WmidT, NTOK, INNER + 2 * NSTATE, INNER, nullptr, 0,
      b_dt, nullptr, nullptr, dtb, Bm, Cm);

  // 5. chunked selective scan
  scan_state_kernel<<<dim3(INNER / 256, NCHUNK, BATCH), 256, 0, stream>>>(dtb, xch, Bm, S, A_chk);
  scan_combine_kernel<<<(BATCH * INNER * NSTATE) / 256, 256, 0, stream>>>(S, A_chk);
  scan_out_kernel<<<dim3(INNER / 256, NCHUNK, BATCH), 256, 0, stream>>>(
      dtb, xch, Bm, Cm, S, zbf, Dvec, ygated);

  // 6. out = ygated @ W_out  (ygated overwrote xin)
  gemm_bt_kernel<0><<<dim3(HID / 128, NTOK / 128), 256, 0, stream>>>(
      ygated, WoutT, NTOK, HID, INNER, out, HID,
      nullptr, nullptr, nullptr, nullptr, nullptr, nullptr);
}

// Round 5
// 463.520 us; speedup vs baseline: 1.0320x; 1.0320x over previous
//
#include <hip/hip_runtime.h>
#include <hip/hip_bf16.h>
#include <math.h>

#define BATCH  2
#define SEQ    2048
#define HID    1024
#define INNER  2048
#define NSTATE 64
#define NTOK   (BATCH * SEQ)
#define TCHUNK 64
#define NCHUNK (SEQ / TCHUNK)

typedef __bf16 bf16x8 __attribute__((ext_vector_type(8)));
typedef float  f32x4  __attribute__((ext_vector_type(4)));

typedef const __attribute__((address_space(1))) char* gas_ptr;
typedef __attribute__((address_space(3))) char*       las_ptr;

__device__ __forceinline__ void gload16(const void* g, void* l) {
  __builtin_amdgcn_global_load_lds((gas_ptr)g, (las_ptr)l, 16, 0, 0);
}

__device__ __forceinline__ unsigned short f2bf(float f) {
  __hip_bfloat16 h = __float2bfloat16(f);
  return __builtin_bit_cast(unsigned short, h);
}
__device__ __forceinline__ float bf2f(unsigned short u) {
  unsigned int x = ((unsigned int)u) << 16;
  return __builtin_bit_cast(float, x);
}

// ---------------------------------------------------------------- cvt fp32->bf16
__global__ __launch_bounds__(256) void cvt_f32_bf16_kernel(
    const float* __restrict__ in, __hip_bfloat16* __restrict__ out, int n4) {
  int i = blockIdx.x * 256 + threadIdx.x;
  if (i >= n4) return;
  float4 v = ((const float4*)in)[i];
  ushort4 u;
  u.x = f2bf(v.x); u.y = f2bf(v.y); u.z = f2bf(v.z); u.w = f2bf(v.w);
  ((ushort4*)out)[i] = u;
}

// ------------------------------------------------- transpose fp32 [R][C] -> bf16 [C][ostride]
__global__ __launch_bounds__(256) void transpose_cvt_kernel(
    const float* __restrict__ in, __hip_bfloat16* __restrict__ out,
    int R, int C, int ostride) {
  __shared__ float tile[32][33];
  int tx = threadIdx.x & 31, ty = threadIdx.x >> 5;
  int c0 = blockIdx.x * 32, r0 = blockIdx.y * 32;
#pragma unroll
  for (int i = 0; i < 4; ++i)
    tile[ty + 8 * i][tx] = in[(size_t)(r0 + ty + 8 * i) * C + c0 + tx];
  __syncthreads();
#pragma unroll
  for (int i = 0; i < 4; ++i)
    out[(size_t)(c0 + ty + 8 * i) * ostride + r0 + tx] =
        __float2bfloat16(tile[tx][ty + 8 * i]);
}

// ---------------------------------------------------------------- GEMM: A[M,K] x Bt[N,K] -> C[M,N]
// 2-phase pipelined: double-buffered LDS, counted vmcnt(4) across raw s_barrier,
// next-tile global_load_lds issued BEFORE current-tile compute. XCD-swizzled 1-D grid.
// EPI 0: fp32 store to Cout (ldc).
// EPI 1: split bf16 store: col<INNER -> o0 (xin), else -> o1 (z).
// EPI 2: mamba mid: col<INNER -> dt=softplus(v+bdt) to f0; next 64 -> f1 (Bm); next 64 -> f2 (Cm).
template <int EPI>
__global__ __launch_bounds__(256) void gemm_bt_kernel(
    const __hip_bfloat16* __restrict__ A, const __hip_bfloat16* __restrict__ Bt,
    int M, int N, int K, int gridN, int nwg,
    float* __restrict__ Cout, int ldc,
    const float* __restrict__ bdt,
    __hip_bfloat16* __restrict__ o0, __hip_bfloat16* __restrict__ o1,
    float* __restrict__ f0, float* __restrict__ f1, float* __restrict__ f2) {
  __shared__ __align__(16) __hip_bfloat16 As[2][128 * 32];
  __shared__ __align__(16) __hip_bfloat16 Bs[2][128 * 32];
  const int tid = threadIdx.x;
  const int lane = tid & 63;
  const int wave = tid >> 6;
  const int wr = wave >> 1, wc = wave & 1;

  // bijective XCD-aware swizzle (m204): consecutive wg on one XCD share an A-panel.
  const int orig = blockIdx.x;
  const int q = nwg >> 3, r = nwg & 7;
  const int xcd = orig & 7, seq = orig >> 3;
  const int wg = (xcd < r ? xcd * (q + 1) : r * (q + 1) + (xcd - r) * q) + seq;
  const int m0 = (wg / gridN) * 128;
  const int n0 = (wg % gridN) * 128;

  const int lrow = lane & 15, lk = lane >> 4;

  f32x4 acc[4][4];
#pragma unroll
  for (int i = 0; i < 4; ++i)
#pragma unroll
    for (int j = 0; j < 4; ++j)
#pragma unroll
      for (int r2 = 0; r2 < 4; ++r2) acc[i][j][r2] = 0.f;

  // staging: wave w stages rows [w*32, w*32+32) of both A and B tiles.
  const int srow = wave * 32;
  const int lr = lane >> 2;
  const int lc = (lane & 3) * 8;
  const __hip_bfloat16* Ag0 = A + (size_t)(m0 + srow + lr) * K + lc;
  const __hip_bfloat16* Ag1 = A + (size_t)(m0 + srow + 16 + lr) * K + lc;
  const __hip_bfloat16* Bg0 = Bt + (size_t)(n0 + srow + lr) * K + lc;
  const __hip_bfloat16* Bg1 = Bt + (size_t)(n0 + srow + 16 + lr) * K + lc;
  __hip_bfloat16* lA0[2] = {&As[0][srow * 32], &As[1][srow * 32]};
  __hip_bfloat16* lA1[2] = {&As[0][(srow + 16) * 32], &As[1][(srow + 16) * 32]};
  __hip_bfloat16* lB0[2] = {&Bs[0][srow * 32], &Bs[1][srow * 32]};
  __hip_bfloat16* lB1[2] = {&Bs[0][(srow + 16) * 32], &Bs[1][(srow + 16) * 32]};

#define STAGE(kk, bsel)                  \
  do {                                   \
    const size_t off = (size_t)(kk) * 32;\
    gload16(Ag0 + off, lA0[bsel]);       \
    gload16(Ag1 + off, lA1[bsel]);       \
    gload16(Bg0 + off, lB0[bsel]);       \
    gload16(Bg1 + off, lB1[bsel]);       \
  } while (0)

  const int nt = K >> 5;
  STAGE(0, 0);
  int cur = 0;
  for (int t = 0; t < nt; ++t) {
    if (t + 1 < nt) {
      STAGE(t + 1, cur ^ 1);
      asm volatile("s_waitcnt vmcnt(4)" ::: "memory");
    } else {
      asm volatile("s_waitcnt vmcnt(0)" ::: "memory");
    }
    __builtin_amdgcn_s_barrier();  // all waves: buf[cur] staged
    bf16x8 af[4], bv[4];
#pragma unroll
    for (int i = 0; i < 4; ++i) {
      af[i] = *reinterpret_cast<const bf16x8*>(&As[cur][(wr * 64 + i * 16 + lrow) * 32 + lk * 8]);
      bv[i] = *reinterpret_cast<const bf16x8*>(&Bs[cur][(wc * 64 + i * 16 + lrow) * 32 + lk * 8]);
    }
#pragma unroll
    for (int i = 0; i < 4; ++i)
#pragma unroll
      for (int j = 0; j < 4; ++j)
        acc[i][j] = __builtin_amdgcn_mfma_f32_16x16x32_bf16(af[i], bv[j], acc[i][j], 0, 0, 0);
    __builtin_amdgcn_s_barrier();  // all waves done reading buf[cur]; next iter may overwrite
    cur ^= 1;
  }
#undef STAGE

#pragma unroll
  for (int i = 0; i < 4; ++i) {
#pragma unroll
    for (int j = 0; j < 4; ++j) {
#pragma unroll
      for (int r2 = 0; r2 < 4; ++r2) {
        const int row = m0 + wr * 64 + i * 16 + lk * 4 + r2;
        const int col = n0 + wc * 64 + j * 16 + lrow;
        const float v = acc[i][j][r2];
        if constexpr (EPI == 0) {
          Cout[(size_t)row * ldc + col] = v;
        } else if constexpr (EPI == 1) {
          if (col < INNER) o0[(size_t)row * INNER + col] = __float2bfloat16(v);
          else             o1[(size_t)row * INNER + (col - INNER)] = __float2bfloat16(v);
        } else {
          if (col < INNER) {
            const float vv = v + bdt[col];
            const float dt = (vv > 15.f) ? vv : log1pf(expf(vv));
            f0[(size_t)row * INNER + col] = dt;
          } else {
            const int jn = col - INNER;
            if (jn < NSTATE) f1[(size_t)row * NSTATE + jn] = v;
            else             f2[(size_t)row * NSTATE + (jn - NSTATE)] = v;
          }
        }
      }
    }
  }
}

// ---------------------------------------------------------------- causal depthwise conv + silu (bf16 in, bf16 out)
__global__ __launch_bounds__(256) void conv_silu_kernel(
    const __hip_bfloat16* __restrict__ xin, const float* __restrict__ cw,
    const float* __restrict__ cb, __hip_bfloat16* __restrict__ xch) {
  int idx = blockIdx.x * 256 + threadIdx.x;  // NTOK * (INNER/4)
  int cg = idx & 511;
  int tok = idx >> 9;
  int c = cg * 4;
  int l = tok & (SEQ - 1);
  float wv[4][4];
#pragma unroll
  for (int i = 0; i < 4; ++i) {
    float4 w = *(const float4*)&cw[(c + i) * 4];
    wv[i][0] = w.x; wv[i][1] = w.y; wv[i][2] = w.z; wv[i][3] = w.w;
  }
  float4 bias = *(const float4*)&cb[c];
  float r0 = bias.x, r1 = bias.y, r2 = bias.z, r3 = bias.w;
#pragma unroll
  for (int k = 0; k < 4; ++k) {
    const int d = 3 - k;
    if (l >= d) {
      ushort4 xv = *(const ushort4*)&xin[(size_t)(tok - d) * INNER + c];
      r0 = fmaf(bf2f(xv.x), wv[0][k], r0);
      r1 = fmaf(bf2f(xv.y), wv[1][k], r1);
      r2 = fmaf(bf2f(xv.z), wv[2][k], r2);
      r3 = fmaf(bf2f(xv.w), wv[3][k], r3);
    }
  }
  r0 = r0 / (1.f + __expf(-r0));
  r1 = r1 / (1.f + __expf(-r1));
  r2 = r2 / (1.f + __expf(-r2));
  r3 = r3 / (1.f + __expf(-r3));
  ushort4 u;
  u.x = f2bf(r0); u.y = f2bf(r1); u.z = f2bf(r2); u.w = f2bf(r3);
  *(ushort4*)&xch[(size_t)tok * INNER + c] = u;
}

// ---------------------------------------------------------------- scan phase 1 (within-chunk states only)
__global__ __launch_bounds__(256) void scan_state_kernel(
    const float* __restrict__ dtb, const __hip_bfloat16* __restrict__ xch,
    const float* __restrict__ Bm,
    float* __restrict__ S, float* __restrict__ A_chunk) {
  __shared__ float Bsh[TCHUNK][64];
  const int b = blockIdx.z, chunk = blockIdx.y;
  const int c = blockIdx.x * 256 + threadIdx.x;
  const int t0 = chunk * TCHUNK;
  for (int i = threadIdx.x; i < TCHUNK * 16; i += 256) {
    const int row = i >> 4, q = i & 15;
    *(float4*)&Bsh[row][q * 4] =
        *(const float4*)&Bm[((size_t)(b * SEQ + t0 + row)) * NSTATE + q * 4];
  }
  __syncthreads();
  float s[64];
#pragma unroll
  for (int n = 0; n < 64; ++n) s[n] = 0.f;
  float p = 1.f;
  const size_t base = (size_t)(b * SEQ + t0) * INNER + c;
  for (int t = 0; t < TCHUNK; ++t) {
    const float dtv = dtb[base + (size_t)t * INNER];
    const float at = __expf(-dtv);
    const float xc = __bfloat162float(xch[base + (size_t)t * INNER]);
    const float ut = dtv * xc;
    p *= at;
#pragma unroll
    for (int q = 0; q < 16; ++q) {
      const float4 bv = *(const float4*)&Bsh[t][q * 4];
      s[4 * q + 0] = fmaf(at, s[4 * q + 0], ut * bv.x);
      s[4 * q + 1] = fmaf(at, s[4 * q + 1], ut * bv.y);
      s[4 * q + 2] = fmaf(at, s[4 * q + 2], ut * bv.z);
      s[4 * q + 3] = fmaf(at, s[4 * q + 3], ut * bv.w);
    }
  }
  const size_t sbase = ((size_t)(b * NCHUNK + chunk) * INNER + c) * NSTATE;
#pragma unroll
  for (int q = 0; q < 16; ++q)
    *(float4*)&S[sbase + 4 * q] =
        make_float4(s[4 * q], s[4 * q + 1], s[4 * q + 2], s[4 * q + 3]);
  A_chunk[(size_t)(b * NCHUNK + chunk) * INNER + c] = p;
}

// ---------------------------------------------------------------- scan phase 2 (cross-chunk combine, in place)
__global__ __launch_bounds__(256) void scan_combine_kernel(
    float* __restrict__ S, const float* __restrict__ A_chunk) {
  const int idx = blockIdx.x * 256 + threadIdx.x;  // BATCH*INNER*NSTATE
  const int n = idx & 63;
  const int c = (idx >> 6) & (INNER - 1);
  const int b = idx >> 17;
  float s = 0.f;
  for (int k = 0; k < NCHUNK; ++k) {
    const size_t cs = (size_t)(b * NCHUNK + k) * INNER + c;
    const size_t off = cs * NSTATE + n;
    const float loc = S[off];
    S[off] = s;
    s = fmaf(A_chunk[cs], s, loc);
  }
}

// ---------------------------------------------------------------- scan phase 3 (full scan from prefix + skip + gate)
__global__ __launch_bounds__(256) void scan_out_kernel(
    const float* __restrict__ dtb, const __hip_bfloat16* __restrict__ xch,
    const float* __restrict__ Bm, const float* __restrict__ Cm,
    const float* __restrict__ S_in, const __hip_bfloat16* __restrict__ zbf,
    const float* __restrict__ Dv, __hip_bfloat16* __restrict__ ygated) {
  __shared__ float Bsh[TCHUNK][64];
  __shared__ float Csh[TCHUNK][64];
  const int b = blockIdx.z, chunk = blockIdx.y;
  const int c = blockIdx.x * 256 + threadIdx.x;
  const int t0 = chunk * TCHUNK;
  for (int i = threadIdx.x; i < TCHUNK * 16; i += 256) {
    const int row = i >> 4, q = i & 15;
    const size_t src = ((size_t)(b * SEQ + t0 + row)) * NSTATE + q * 4;
    *(float4*)&Bsh[row][q * 4] = *(const float4*)&Bm[src];
    *(float4*)&Csh[row][q * 4] = *(const float4*)&Cm[src];
  }
  __syncthreads();
  float s[64];
  const size_t sbase = ((size_t)(b * NCHUNK + chunk) * INNER + c) * NSTATE;
#pragma unroll
  for (int q = 0; q < 16; ++q) {
    const float4 v = *(const float4*)&S_in[sbase + 4 * q];
    s[4 * q] = v.x; s[4 * q + 1] = v.y; s[4 * q + 2] = v.z; s[4 * q + 3] = v.w;
  }
  const float Dc = Dv[c];
  const size_t base = (size_t)(b * SEQ + t0) * INNER + c;
  for (int t = 0; t < TCHUNK; ++t) {
    const float dtv = dtb[base + (size_t)t * INNER];
    const float at = __expf(-dtv);
    const float xc = __bfloat162float(xch[base + (size_t)t * INNER]);
    const float ut = dtv * xc;
    float y0 = 0.f, y1 = 0.f, y2 = 0.f, y3 = 0.f;
#pragma unroll
    for (int q = 0; q < 16; ++q) {
      const float4 bv = *(const float4*)&Bsh[t][q * 4];
      const float4 cv = *(const float4*)&Csh[t][q * 4];
      s[4 * q + 0] = fmaf(at, s[4 * q + 0], ut * bv.x);
      s[4 * q + 1] = fmaf(at, s[4 * q + 1], ut * bv.y);
      s[4 * q + 2] = fmaf(at, s[4 * q + 2], ut * bv.z);
      s[4 * q + 3] = fmaf(at, s[4 * q + 3], ut * bv.w);
      y0 = fmaf(s[4 * q + 0], cv.x, y0);
      y1 = fmaf(s[4 * q + 1], cv.y, y1);
      y2 = fmaf(s[4 * q + 2], cv.z, y2);
      y3 = fmaf(s[4 * q + 3], cv.w, y3);
    }
    const float yt = fmaf(Dc, xc, (y0 + y1) + (y2 + y3));
    const float z = __bfloat162float(zbf[base + (size_t)t * INNER]);
    const float g = z / (1.f + __expf(-z));
    ygated[base + (size_t)t * INNER] = __float2bfloat16(yt * g);
  }
}

// ---------------------------------------------------------------- launch
extern "C" void kernel_launch(void* const* d_in, const int* in_sizes, int n_in,
                              void* d_out, int out_size, void* d_ws, size_t ws_size,
                              hipStream_t stream) {
  const float* x      = (const float*)d_in[0];
  const float* W_in   = (const float*)d_in[1];
  const float* conv_w = (const float*)d_in[2];
  const float* conv_b = (const float*)d_in[3];
  const float* W_dt   = (const float*)d_in[4];
  const float* b_dt   = (const float*)d_in[5];
  const float* W_B    = (const float*)d_in[6];
  const float* W_C    = (const float*)d_in[7];
  const float* Dvec   = (const float*)d_in[8];
  const float* W_out  = (const float*)d_in[9];
  float* out = (float*)d_out;

  // ---- workspace layout (~127 MiB total) with lifetime-based aliasing ----
  char* p = (char*)d_ws;
  auto alloc = [&](size_t bytes) {
    char* r = p;
    p += (bytes + 255) & ~(size_t)255;
    return r;
  };
  __hip_bfloat16* xin   = (__hip_bfloat16*)alloc((size_t)NTOK * INNER * 2);  // GEMM1 out; later ygated
  __hip_bfloat16* zbf   = (__hip_bfloat16*)alloc((size_t)NTOK * INNER * 2);
  char*           scr   = alloc((size_t)NTOK * INNER * 2);                   // x_bf+WinT; later xch
  __hip_bfloat16* WmidT = (__hip_bfloat16*)alloc((size_t)(INNER + 2 * NSTATE) * INNER * 2);
  __hip_bfloat16* WoutT = (__hip_bfloat16*)alloc((size_t)HID * INNER * 2);
  float*          dtb   = (float*)alloc((size_t)NTOK * INNER * 4);
  float*          Bm    = (float*)alloc((size_t)NTOK * NSTATE * 4);
  float*          Cm    = (float*)alloc((size_t)NTOK * NSTATE * 4);
  float*          S     = (float*)alloc((size_t)BATCH * NCHUNK * INNER * NSTATE * 4);
  float*          A_chk = (float*)alloc((size_t)BATCH * NCHUNK * INNER * 4);

  __hip_bfloat16* x_bf   = (__hip_bfloat16*)scr;                              // 8 MB
  __hip_bfloat16* WinT   = (__hip_bfloat16*)(scr + (size_t)NTOK * HID * 2);   // 8 MB
  __hip_bfloat16* xch    = (__hip_bfloat16*)scr;                              // 16 MB (after GEMM1)
  __hip_bfloat16* ygated = xin;                                               // 16 MB (after conv)

  // 1. conversions / transposes
  cvt_f32_bf16_kernel<<<(NTOK * HID / 4 + 255) / 256, 256, 0, stream>>>(x, x_bf, NTOK * HID / 4);
  transpose_cvt_kernel<<<dim3((2 * INNER) / 32, HID / 32), 256, 0, stream>>>(W_in, WinT, HID, 2 * INNER, HID);
  transpose_cvt_kernel<<<dim3(INNER / 32, INNER / 32), 256, 0, stream>>>(W_dt, WmidT, INNER, INNER, INNER);
  transpose_cvt_kernel<<<dim3(NSTATE / 32, INNER / 32), 256, 0, stream>>>(
      W_B, WmidT + (size_t)INNER * INNER, INNER, NSTATE, INNER);
  transpose_cvt_kernel<<<dim3(NSTATE / 32, INNER / 32), 256, 0, stream>>>(
      W_C, WmidT + (size_t)(INNER + NSTATE) * INNER, INNER, NSTATE, INNER);
  transpose_cvt_kernel<<<dim3(HID / 32, INNER / 32), 256, 0, stream>>>(W_out, WoutT, INNER, HID, INNER);

  // 2. xz = x @ W_in  -> split bf16 (xin | z)
  {
    const int gridN = (2 * INNER) / 128, nwg = gridN * (NTOK / 128);
    gemm_bt_kernel<1><<<nwg, 256, 0, stream>>>(
        x_bf, WinT, NTOK, 2 * INNER, HID, gridN, nwg, nullptr, 0,
        nullptr, xin, zbf, nullptr, nullptr, nullptr);
  }

  // 3. conv + silu  (xin -> xch; overwrites x_bf/WinT region)
  conv_silu_kernel<<<(NTOK * (INNER / 4)) / 256, 256, 0, stream>>>(xin, conv_w, conv_b, xch);

  // 4. mid GEMM (dt|B|C) with fused softplus epilogue
  {
    const int gridN = (INNER + 2 * NSTATE) / 128, nwg = gridN * (NTOK / 128);
    gemm_bt_kernel<2><<<nwg, 256, 0, stream>>>(
        xch, WmidT, NTOK, INNER + 2 * NSTATE, INNER, gridN, nwg, nullptr, 0,
        b_dt, nullptr, nullptr, dtb, Bm, Cm);
  }

  // 5. chunked selective scan
  scan_state_kernel<<<dim3(INNER / 256, NCHUNK, BATCH), 256, 0, stream>>>(dtb, xch, Bm, S, A_chk);
  scan_combine_kernel<<<(BATCH * INNER * NSTATE) / 256, 256, 0, stream>>>(S, A_chk);
  scan_out_kernel<<<dim3(INNER / 256, NCHUNK, BATCH), 256, 0, stream>>>(
      dtb, xch, Bm, Cm, S, zbf, Dvec, ygated);

  // 6. out = ygated @ W_out  (ygated overwrote xin)
  {
    const int gridN = HID / 128, nwg = gridN * (NTOK / 128);
    gemm_bt_kernel<0><<<nwg, 256, 0, stream>>>(
        ygated, WoutT, NTOK, HID, INNER, gridN, nwg, out, HID,
        nullptr, nullptr, nullptr, nullptr, nullptr, nullptr);
  }
}